// Round 1
// baseline (138.835 us; speedup 1.0000x reference)
//
#include <hip/hip_runtime.h>
#include <hip/hip_bf16.h>

// NT-Xent with more negatives: N=2048, D=128, k=4 augs.
// sim = norm(z[4096,128]) @ norm(z_all[8192,128])^T * 2   (T=0.5)
// loss = mean_rows( logsumexp(masked sim) - pos )

#define NN      2048
#define DD      128
#define TWO_N   4096
#define FOUR_N  8192
#define COL_TILES 64   // 8192 / 128
#define ROW_TILES 64   // 4096 / 64

using frag_ab = __attribute__((ext_vector_type(8))) short;  // 8 bf16
using f32x4   = __attribute__((ext_vector_type(4))) float;

__device__ inline float bf2f(short u) {
  unsigned int x = ((unsigned int)(unsigned short)u) << 16;
  return __uint_as_float(x);
}

// ---------------- Kernel 1: L2-normalize rows, write bf16 ----------------
// One wave per row; 8192 rows -> 2048 blocks x 256 threads.
__global__ __launch_bounds__(256) void knorm(const float* __restrict__ p0,
                                             const float* __restrict__ p1,
                                             const float* __restrict__ p2,
                                             const float* __restrict__ p3,
                                             short* __restrict__ Bn) {
  int wave = threadIdx.x >> 6, lane = threadIdx.x & 63;
  int row = blockIdx.x * 4 + wave;                 // 0..8191
  int q = row >> 11, idx = row & (NN - 1);
  const float* src = (q == 0) ? p0 : (q == 1) ? p1 : (q == 2) ? p2 : p3;
  const float2* s2 = (const float2*)(src + (size_t)idx * DD);
  float2 v = s2[lane];                             // elems 2*lane, 2*lane+1
  float ss = v.x * v.x + v.y * v.y;
  #pragma unroll
  for (int sh = 1; sh < 64; sh <<= 1) ss += __shfl_xor(ss, sh, 64);
  float inv = 1.0f / fmaxf(sqrtf(ss), 1e-8f);
  __hip_bfloat162 o;
  o.x = __float2bfloat16(v.x * inv);
  o.y = __float2bfloat16(v.y * inv);
  ((__hip_bfloat162*)(Bn + (size_t)row * DD))[lane] = o;
}

// ---------------- Kernel 2: fused GEMM tile + partial row-LSE ----------------
// Block = 256 thr (4 waves). Tile: 64 rows x 128 cols. Grid (64,64).
// Wave w handles rows [rowTile*64 + w*16, +16), all 128 cols of the col tile.
// MFMA 16x16x32 bf16, A/B fragments loaded straight from global (L1/L2-hot).
__global__ __launch_bounds__(256) void kgemm(const short* __restrict__ Bn,
                                             float* __restrict__ pM,
                                             float* __restrict__ pS) {
  int wave = threadIdx.x >> 6, lane = threadIdx.x & 63;
  int quad = lane >> 4, l16 = lane & 15;
  int rowBase = blockIdx.x * 64 + wave * 16;       // A rows (first 4096 of Bn)
  int colBase = blockIdx.y * 128;                  // B rows (all 8192)
  int colTile = blockIdx.y;

  f32x4 acc[8];
  #pragma unroll
  for (int f = 0; f < 8; ++f) acc[f] = (f32x4){0.f, 0.f, 0.f, 0.f};

  const short* Arow = Bn + (size_t)(rowBase + l16) * DD + quad * 8;
  const short* Brow = Bn + (size_t)(colBase + l16) * DD + quad * 8;

  #pragma unroll
  for (int k = 0; k < 4; ++k) {
    frag_ab a = *(const frag_ab*)(Arow + k * 32);
    #pragma unroll
    for (int f = 0; f < 8; ++f) {
      frag_ab b = *(const frag_ab*)(Brow + (size_t)f * 16 * DD + k * 32);
      acc[f] = __builtin_amdgcn_mfma_f32_16x16x32_bf16(a, b, acc[f], 0, 0, 0);
    }
  }

  // Epilogue: scale x2 (temperature), mask, per-row online max/sum-exp.
  // C/D layout: value acc[f][r] = sim[rowBase + quad*4 + r][colBase + f*16 + l16]
  #pragma unroll
  for (int r = 0; r < 4; ++r) {
    int gr = rowBase + quad * 4 + r;               // global row (0..4095)
    int idx = gr & (NN - 1);
    int half = gr >> 11;                           // 0 or 1
    float vals[8];
    float m = -1e30f;
    #pragma unroll
    for (int f = 0; f < 8; ++f) {
      int c = colBase + f * 16 + l16;              // global col (0..8191)
      float v = acc[f][r] * 2.0f;
      bool masked = ((c & (NN - 1)) == idx) && ((c >> 11) != (1 - half));
      v = masked ? -1e30f : v;
      vals[f] = v;
      m = fmaxf(m, v);
    }
    #pragma unroll
    for (int sh = 1; sh < 16; sh <<= 1) m = fmaxf(m, __shfl_xor(m, sh, 64));
    float s = 0.f;
    #pragma unroll
    for (int f = 0; f < 8; ++f) s += __expf(vals[f] - m);
    #pragma unroll
    for (int sh = 1; sh < 16; sh <<= 1) s += __shfl_xor(s, sh, 64);
    if (l16 == 0) {
      pM[(size_t)gr * COL_TILES + colTile] = m;
      pS[(size_t)gr * COL_TILES + colTile] = s;
    }
  }
}

// ---------------- Kernel 3: merge partials -> LSE, compute pos, row loss ----
// One wave per row; 4096 rows -> 1024 blocks x 256 threads.
__global__ __launch_bounds__(256) void krow(const short* __restrict__ Bn,
                                            const float* __restrict__ pM,
                                            const float* __restrict__ pS,
                                            float* __restrict__ rowLoss) {
  int wave = threadIdx.x >> 6, lane = threadIdx.x & 63;
  int gr = blockIdx.x * 4 + wave;                  // 0..4095
  float m = pM[(size_t)gr * COL_TILES + lane];     // lane j -> col tile j
  float s = pS[(size_t)gr * COL_TILES + lane];
  float M = m;
  #pragma unroll
  for (int sh = 1; sh < 64; sh <<= 1) M = fmaxf(M, __shfl_xor(M, sh, 64));
  float S = s * __expf(m - M);
  #pragma unroll
  for (int sh = 1; sh < 64; sh <<= 1) S += __shfl_xor(S, sh, 64);
  float lse = M + __logf(S);

  int idx = gr & (NN - 1), half = gr >> 11;
  int tgt = (1 - half) * NN + idx;                 // positive column
  const short* a = Bn + (size_t)gr * DD;
  const short* b = Bn + (size_t)tgt * DD;
  float dot = bf2f(a[2 * lane]) * bf2f(b[2 * lane])
            + bf2f(a[2 * lane + 1]) * bf2f(b[2 * lane + 1]);
  #pragma unroll
  for (int sh = 1; sh < 64; sh <<= 1) dot += __shfl_xor(dot, sh, 64);
  float pos = dot * 2.0f;

  if (lane == 0) rowLoss[gr] = lse - pos;
}

// ---------------- Kernel 4: deterministic final reduce ----------------
__global__ __launch_bounds__(256) void kfinal(const float* __restrict__ rowLoss,
                                              float* __restrict__ out) {
  float s = 0.f;
  for (int i = threadIdx.x; i < TWO_N; i += 256) s += rowLoss[i];
  #pragma unroll
  for (int sh = 1; sh < 64; sh <<= 1) s += __shfl_xor(s, sh, 64);
  __shared__ float wsum[4];
  if ((threadIdx.x & 63) == 0) wsum[threadIdx.x >> 6] = s;
  __syncthreads();
  if (threadIdx.x == 0)
    out[0] = (wsum[0] + wsum[1] + wsum[2] + wsum[3]) * (1.0f / (float)TWO_N);
}

extern "C" void kernel_launch(void* const* d_in, const int* in_sizes, int n_in,
                              void* d_out, int out_size, void* d_ws, size_t ws_size,
                              hipStream_t stream) {
  const float* p0 = (const float*)d_in[0];
  const float* p1 = (const float*)d_in[1];
  const float* p2 = (const float*)d_in[2];
  const float* p3 = (const float*)d_in[3];

  // ws layout: Bn bf16 [8192][128] (2 MB) | pM f32 [4096][64] (1 MB)
  //          | pS f32 [4096][64] (1 MB)  | rowLoss f32 [4096] (16 KB)
  short* Bn = (short*)d_ws;
  float* pM = (float*)((char*)d_ws + (size_t)FOUR_N * DD * sizeof(short));
  float* pS = pM + (size_t)TWO_N * COL_TILES;
  float* rowLoss = pS + (size_t)TWO_N * COL_TILES;

  knorm<<<FOUR_N / 4, 256, 0, stream>>>(p0, p1, p2, p3, Bn);
  kgemm<<<dim3(ROW_TILES, COL_TILES), 256, 0, stream>>>(Bn, pM, pS);
  krow<<<TWO_N / 4, 256, 0, stream>>>(Bn, pM, pS, rowLoss);
  kfinal<<<1, 256, 0, stream>>>(rowLoss, (float*)d_out);
}

// Round 2
// 111.131 us; speedup vs baseline: 1.2493x; 1.2493x over previous
//
#include <hip/hip_runtime.h>
#include <hip/hip_bf16.h>

// NT-Xent with more negatives: N=2048, D=128, k=4 augs.
// sim = norm(z[4096,128]) @ norm(z_all[8192,128])^T * 2   (T=0.5)
// loss = mean_rows( logsumexp(masked sim) - pos )

#define NN      2048
#define DD      128
#define TWO_N   4096
#define FOUR_N  8192
#define BM      128
#define BN      128
#define CT      64     // 8192 / BN column tiles

using frag_ab = __attribute__((ext_vector_type(8))) short;  // 8 bf16 = 16 B
using f32x4   = __attribute__((ext_vector_type(4))) float;

__device__ inline void gl_lds16(const short* g, short* l) {
  __builtin_amdgcn_global_load_lds(
      (const __attribute__((address_space(1))) void*)g,
      (__attribute__((address_space(3))) void*)l, 16, 0, 0);
}

// ---------------- Kernel 1: L2-normalize rows -> bf16; zero the output ------
__global__ __launch_bounds__(256) void knorm(const float* __restrict__ p0,
                                             const float* __restrict__ p1,
                                             const float* __restrict__ p2,
                                             const float* __restrict__ p3,
                                             short* __restrict__ Bn,
                                             float* __restrict__ out) {
  if (blockIdx.x == 0 && threadIdx.x == 0) out[0] = 0.0f;  // init for krow atomics
  int wave = threadIdx.x >> 6, lane = threadIdx.x & 63;
  int row = blockIdx.x * 4 + wave;                 // 0..8191
  int q = row >> 11, idx = row & (NN - 1);
  const float* src = (q == 0) ? p0 : (q == 1) ? p1 : (q == 2) ? p2 : p3;
  const float2* s2 = (const float2*)(src + (size_t)idx * DD);
  float2 v = s2[lane];                             // elems 2*lane, 2*lane+1
  float ss = v.x * v.x + v.y * v.y;
  #pragma unroll
  for (int sh = 1; sh < 64; sh <<= 1) ss += __shfl_xor(ss, sh, 64);
  float inv = 1.0f / fmaxf(sqrtf(ss), 1e-8f);
  __hip_bfloat162 o;
  o.x = __float2bfloat16(v.x * inv);
  o.y = __float2bfloat16(v.y * inv);
  ((__hip_bfloat162*)(Bn + (size_t)row * DD))[lane] = o;
}

// ---------------- Kernel 2: 128x128 tile GEMM + fused partial LSE -----------
// m97 structure: global_load_lds staging, ds_read_b128 fragments, 4 waves
// each computing a 64x64 quadrant as 4x4 grid of 16x16x32 bf16 MFMAs.
// Emits one (max, sumexp) partial per (row, 128-col tile) -> pMS[CT][TWO_N].
__global__ __launch_bounds__(256) void kgemm(const short* __restrict__ Bn,
                                             float2* __restrict__ pMS) {
  __shared__ short sA[BM * DD];   // 32 KB
  __shared__ short sB[BN * DD];   // 32 KB
  __shared__ float sM[BM][2];
  __shared__ float sS[BM][2];

  int t = threadIdx.x, wave = t >> 6, lane = t & 63;
  int quad = lane >> 4, l16 = lane & 15;

  // A tile rows blockIdx.x*128.. ; B tile rows blockIdx.y*128..  (contiguous!)
  const short* gA = Bn + (size_t)blockIdx.x * BM * DD;
  const short* gB = Bn + (size_t)blockIdx.y * BN * DD;
  #pragma unroll
  for (int i = 0; i < 8; ++i) {
    int c0 = i * 256 + wave * 64;                  // lane-0 chunk index
    gl_lds16(gA + (size_t)(c0 + lane) * 8, sA + (size_t)c0 * 8);
    gl_lds16(gB + (size_t)(c0 + lane) * 8, sB + (size_t)c0 * 8);
  }
  __syncthreads();   // barrier drains vmcnt -> LDS staging complete

  int rowHalf = wave >> 1, colHalf = wave & 1;
  f32x4 acc[4][4];
  #pragma unroll
  for (int rf = 0; rf < 4; ++rf)
    #pragma unroll
    for (int cf = 0; cf < 4; ++cf) acc[rf][cf] = (f32x4){0.f, 0.f, 0.f, 0.f};

  #pragma unroll
  for (int k = 0; k < 4; ++k) {
    frag_ab a[4], b[4];
    #pragma unroll
    for (int rf = 0; rf < 4; ++rf)
      a[rf] = *(const frag_ab*)&sA[(rowHalf * 64 + rf * 16 + l16) * DD + k * 32 + quad * 8];
    #pragma unroll
    for (int cf = 0; cf < 4; ++cf)
      b[cf] = *(const frag_ab*)&sB[(colHalf * 64 + cf * 16 + l16) * DD + k * 32 + quad * 8];
    #pragma unroll
    for (int rf = 0; rf < 4; ++rf)
      #pragma unroll
      for (int cf = 0; cf < 4; ++cf)
        acc[rf][cf] = __builtin_amdgcn_mfma_f32_16x16x32_bf16(a[rf], b[cf], acc[rf][cf], 0, 0, 0);
  }

  // Epilogue: x2 temperature, mask, per-row (max, sumexp) over this wave's
  // 64 cols, then merge the two col-halves through LDS.
  int grBase = blockIdx.x * BM;
  int colBase = blockIdx.y * BN + colHalf * 64;
  #pragma unroll
  for (int rf = 0; rf < 4; ++rf) {
    #pragma unroll
    for (int r = 0; r < 4; ++r) {
      int rowLocal = rowHalf * 64 + rf * 16 + quad * 4 + r;
      int gr = grBase + rowLocal;
      int idx = gr & (NN - 1);
      int notblk = 1 - (gr >> 11);                 // exempt (positive) block
      float vals[4];
      float m = -1e30f;
      #pragma unroll
      for (int cf = 0; cf < 4; ++cf) {
        int c = colBase + cf * 16 + l16;
        float v = acc[rf][cf][r] * 2.0f;
        bool masked = ((c & (NN - 1)) == idx) && ((c >> 11) != notblk);
        v = masked ? -1e30f : v;
        vals[cf] = v;
        m = fmaxf(m, v);
      }
      #pragma unroll
      for (int sh = 1; sh < 16; sh <<= 1) m = fmaxf(m, __shfl_xor(m, sh, 64));
      float s = 0.f;
      #pragma unroll
      for (int cf = 0; cf < 4; ++cf) s += __expf(vals[cf] - m);
      #pragma unroll
      for (int sh = 1; sh < 16; sh <<= 1) s += __shfl_xor(s, sh, 64);
      if (l16 == 0) { sM[rowLocal][colHalf] = m; sS[rowLocal][colHalf] = s; }
    }
  }
  __syncthreads();
  if (t < BM) {
    float m0 = sM[t][0], m1 = sM[t][1];
    float s0 = sS[t][0], s1 = sS[t][1];
    float M = fmaxf(m0, m1);
    float S = s0 * __expf(m0 - M) + s1 * __expf(m1 - M);
    pMS[(size_t)blockIdx.y * TWO_N + grBase + t] = make_float2(M, S);  // coalesced
  }
}

// ---------------- Kernel 3: merge partials, pos, block-reduce, atomic -------
// 1024 threads = 16 waves = 16 rows per block; 256 blocks; 1 atomicAdd/block.
__global__ __launch_bounds__(1024) void krow(const short* __restrict__ Bn,
                                             const float2* __restrict__ pMS,
                                             float* __restrict__ out) {
  int t = threadIdx.x, w = t >> 6, lane = t & 63;
  int gr = blockIdx.x * 16 + w;                    // 0..4095
  float2 p = pMS[(size_t)lane * TWO_N + gr];       // lane j -> col tile j
  float M = p.x;
  #pragma unroll
  for (int sh = 1; sh < 64; sh <<= 1) M = fmaxf(M, __shfl_xor(M, sh, 64));
  float S = p.y * __expf(p.x - M);
  #pragma unroll
  for (int sh = 1; sh < 64; sh <<= 1) S += __shfl_xor(S, sh, 64);
  float lse = M + __logf(S);

  int idx = gr & (NN - 1), half = gr >> 11;
  int tgt = (1 - half) * NN + idx;                 // positive column
  unsigned int ua = ((const unsigned int*)(Bn + (size_t)gr * DD))[lane];
  unsigned int ub = ((const unsigned int*)(Bn + (size_t)tgt * DD))[lane];
  float a0 = __uint_as_float((ua & 0xffffu) << 16);
  float a1 = __uint_as_float(ua & 0xffff0000u);
  float b0 = __uint_as_float((ub & 0xffffu) << 16);
  float b1 = __uint_as_float(ub & 0xffff0000u);
  float dot = a0 * b0 + a1 * b1;
  #pragma unroll
  for (int sh = 1; sh < 64; sh <<= 1) dot += __shfl_xor(dot, sh, 64);
  float loss = lse - 2.0f * dot;

  __shared__ float wsum[16];
  if (lane == 0) wsum[w] = loss;
  __syncthreads();
  if (t == 0) {
    float s = 0.f;
    #pragma unroll
    for (int i = 0; i < 16; ++i) s += wsum[i];
    atomicAdd(out, s * (1.0f / (float)TWO_N));
  }
}

extern "C" void kernel_launch(void* const* d_in, const int* in_sizes, int n_in,
                              void* d_out, int out_size, void* d_ws, size_t ws_size,
                              hipStream_t stream) {
  (void)in_sizes; (void)n_in; (void)out_size; (void)ws_size;
  const float* p0 = (const float*)d_in[0];
  const float* p1 = (const float*)d_in[1];
  const float* p2 = (const float*)d_in[2];
  const float* p3 = (const float*)d_in[3];

  // ws layout: Bn bf16 [8192][128] (2 MB) | pMS float2 [64][4096] (2 MB)
  short* Bn = (short*)d_ws;
  float2* pMS = (float2*)((char*)d_ws + (size_t)FOUR_N * DD * sizeof(short));
  float* out = (float*)d_out;

  knorm<<<FOUR_N / 4, 256, 0, stream>>>(p0, p1, p2, p3, Bn, out);
  kgemm<<<dim3(TWO_N / BM, FOUR_N / BN), 256, 0, stream>>>(Bn, pMS);
  krow<<<TWO_N / 16, 1024, 0, stream>>>(Bn, pMS, out);
}